// Round 16
// baseline (357.943 us; speedup 1.0000x reference)
//
#include <hip/hip_runtime.h>

typedef float vf4 __attribute__((ext_vector_type(4)));
typedef int vi4 __attribute__((ext_vector_type(4)));
typedef int vi2 __attribute__((ext_vector_type(2)));
typedef short short8 __attribute__((ext_vector_type(8)));
typedef unsigned short ushort8 __attribute__((ext_vector_type(8)));

#define LL 1024
#define OO 128
#define BBATCH 4096
#define NS 511          // sites per sweep
#define NP 256          // pair steps per sweep (255 real pairs + 1 w/ phantom)
#define SITE_F 8192     // elements per site tensor (64*2*64)
#define PAIR_U16 16384  // ushorts per pair fragment block (64 x 256 bf16)
#define PAIR_F 8192     // same block viewed as floats

// ---- async global->LDS ----
__device__ __forceinline__ void gld_lds16(const float* g, float* l) {
  __builtin_amdgcn_global_load_lds(
      (const __attribute__((address_space(1))) unsigned int*)g,
      (__attribute__((address_space(3))) unsigned int*)l, 16, 0, 0);
}

__device__ __forceinline__ unsigned short f2bf(float v) {
  const unsigned uu = __builtin_bit_cast(unsigned, v);
  return (unsigned short)((uu + 0x7FFFu + ((uu >> 16) & 1u)) >> 16);  // RNE
}

// ---- one-shot: pair transfer matrices D = A_i*A_j - I, bf16 A-frag-major ----
// frag layout (16x16x32 A-operand, K=256): f = mt*8+s; element at (lane,j):
//   m = 16mt + (lane&15); k = 32s + 8(lane>>4) + j
//   contraction row kk = 16(s>>1) + 4(lane>>4) + (j>>1); p = s&1; q = j&1
// dir0 (left): D[(l=kk,p,q)][m] = sum_r Li[l,p,r]*Lj[r,q,m] - d(l,m)
// dir1 (right): D[(r=kk,p,q)][l=m] = sum_t Rs0[l,q,t]*Rs1[t,p,r] - d(l,r)
// pair NP-1: phantom second site (identity, phi=(1,0) at runtime).
__global__ __launch_bounds__(256) void prep_pair(const float* __restrict__ lsrc,
                                                 const float* __restrict__ rsrc,
                                                 unsigned short* __restrict__ Wp) {
  __shared__ float X[8192];
  __shared__ float YT[8192];
  const int pair = blockIdx.x, dir = blockIdx.y;
  const int tid = threadIdx.x;
  unsigned short* dst = Wp + ((size_t)dir * NP + pair) * PAIR_U16;
  const bool ph = (pair == NP - 1);

  const float* Xg;
  const float* Yg = nullptr;
  if (dir == 0) {
    Xg = lsrc + (size_t)(2 * pair) * SITE_F;             // first applied
    if (!ph) Yg = lsrc + (size_t)(2 * pair + 1) * SITE_F;
  } else {
    const int s1 = 510 - 2 * pair;                       // first applied
    if (!ph) {
      Xg = rsrc + (size_t)(s1 - 1) * SITE_F;             // second applied
      Yg = rsrc + (size_t)s1 * SITE_F;
    } else {
      Xg = rsrc;                                         // site 0, only step
    }
  }
#pragma unroll
  for (int q8 = 0; q8 < 8; q8++)
    *(vf4*)&X[(q8 * 256 + tid) * 4] = *(const vf4*)&Xg[(q8 * 256 + tid) * 4];
  if (!ph) {
    // YT[(B*64 + C)*64 + A] = Y[A*128 + B*64 + C]
#pragma unroll
    for (int q8 = 0; q8 < 8; q8++) {
      const int e = (q8 * 256 + tid) * 4;
      const vf4 v = *(const vf4*)&Yg[e];
      const int A = e >> 7, B = (e >> 6) & 1, C = e & 63;
#pragma unroll
      for (int k2 = 0; k2 < 4; k2++)
        YT[(B * 64 + C + k2) * 64 + A] = v[k2];
    }
  }
  __syncthreads();

  const int kk = tid >> 2;
  const int p = (tid >> 1) & 1, q = tid & 1;
  const int s = 2 * (kk >> 4) + p;
  const int g = (kk >> 2) & 3;
  const int j = 2 * (kk & 3) + q;

  vf4 row[16];
  if (dir == 0) {
#pragma unroll
    for (int w = 0; w < 16; w++)
      row[w] = *(const vf4*)&X[kk * 128 + p * 64 + w * 4];
  } else if (!ph) {
#pragma unroll
    for (int w = 0; w < 16; w++)
      row[w] = *(const vf4*)&YT[(p * 64 + kk) * 64 + w * 4];
  }

  for (int mm = 0; mm < 64; mm++) {
    float val;
    if (dir == 0) {
      if (!ph) {
        float d = 0.f;
#pragma unroll
        for (int w = 0; w < 16; w++) {
          const vf4 y = *(const vf4*)&YT[(q * 64 + mm) * 64 + w * 4];
          d += row[w][0] * y[0] + row[w][1] * y[1] +
               row[w][2] * y[2] + row[w][3] * y[3];
        }
        val = d - ((kk == mm) ? 1.f : 0.f);
      } else {
        val = row[mm >> 2][mm & 3] - ((kk == mm) ? 1.f : 0.f);
      }
    } else {
      if (!ph) {
        float d = 0.f;
#pragma unroll
        for (int w = 0; w < 16; w++) {
          const vf4 xv = *(const vf4*)&X[mm * 128 + q * 64 + w * 4];
          d += xv[0] * row[w][0] + xv[1] * row[w][1] +
               xv[2] * row[w][2] + xv[3] * row[w][3];
        }
        val = d - ((mm == kk) ? 1.f : 0.f);
      } else {
        val = X[mm * 128 + p * 64 + kk] - ((mm == kk) ? 1.f : 0.f);
      }
    }
    const int mt = mm >> 4, c = mm & 15;
    dst[(size_t)(((mt * 8 + s) * 64) + (g << 4) + c) * 8 + j] = f2bf(val);
  }
}

// ---- one-shot: pack center C[l][r][o] into per-o A-frags (bf16) ----
__global__ __launch_bounds__(256) void prep2(const float* __restrict__ center,
                                             unsigned short* __restrict__ Cf) {
  __shared__ float S[4096];        // C[:,:,o] slab, [l*64+r]
  const int o = blockIdx.x;
  const int tid = threadIdx.x;
#pragma unroll
  for (int k = 0; k < 16; k++) {
    const int idx = k * 256 + tid;
    S[idx] = center[(size_t)idx * 128 + o];
  }
  __syncthreads();
#pragma unroll
  for (int q = 0; q < 2; q++) {
    const int slot = q * 256 + tid;           // 0..511 = f*64 + lane
    const int lane = slot & 63, f = slot >> 6;
    const int mt = f >> 1, s = f & 1;
    const int g = lane >> 4, c = lane & 15;
    const int l = 16 * mt + c;
    ushort8 t;
#pragma unroll
    for (int j = 0; j < 8; j++) {
      const int r = 32 * s + 8 * g + j;
      t[j] = f2bf(S[l * 64 + r]);
    }
    *(ushort8*)&Cf[(size_t)((o * 8 + f) * 64 + lane) * 8] = t;
  }
}

// ---- stage one 2-pair group (64KB) with 128 threads ----
#define STAGE_GROUP(G, BUF)                                                    \
  {                                                                            \
    _Pragma("unroll")                                                          \
    for (int s2 = 0; s2 < 2; s2++) {                                           \
      const float* src_ = Wf + (size_t)(2 * (G) + s2) * PAIR_F;                \
      float* d_ = &ring[BUF][s2][0];                                           \
      _Pragma("unroll")                                                        \
      for (int q8 = 0; q8 < 16; q8++)                                          \
        gld_lds16(src_ + q8 * 512 + tid * 4, d_ + q8 * 512 + tid * 4);         \
    }                                                                          \
  }

// ---- per-pair body ----
#define PBODY(PR, BUF, S2)                                                     \
  {                                                                            \
    const int pr_ = (PR);                                                      \
    const float* rb = &ring[BUF][S2][0];                                       \
    vf4 FC[32];                                                                \
    _Pragma("unroll")                                                          \
    for (int f = 0; f < 32; f++)                                               \
      FC[f] = *(const vf4*)&rb[f * 256 + lane * 4];                            \
    const int npr = pr_ + 1;                                                   \
    float xiN = 0.f, xjN = 0.f;                                                \
    if (npr < NP) {                                                            \
      xiN = xrow[dir ? (1022 - 2 * npr) : (1 + 2 * npr)];                      \
      xjN = (npr == NP - 1) ? 0.f                                              \
                            : xrow[dir ? (1021 - 2 * npr) : (2 + 2 * npr)];    \
    }                                                                          \
    const float keff = (ci + si) * (cj + sj);                                  \
    const float w00 = ci * cj, w01 = ci * sj;                                  \
    const float w10 = si * cj, w11 = si * sj;                                  \
    vf4 acc[4];                                                                \
    _Pragma("unroll")                                                          \
    for (int mt = 0; mt < 4; mt++) {                                           \
      vf4 z;                                                                   \
      z[0] = keff * u[mt][0]; z[1] = keff * u[mt][1];                          \
      z[2] = keff * u[mt][2]; z[3] = keff * u[mt][3];                          \
      acc[mt] = z;                                                             \
    }                                                                          \
    _Pragma("unroll")                                                          \
    for (int s = 0; s < 8; s++) {                                              \
      const float wa = (s & 1) ? w10 : w00;                                    \
      const float wb = (s & 1) ? w11 : w01;                                    \
      int pk[4];                                                               \
      _Pragma("unroll")                                                        \
      for (int t = 0; t < 4; t++) {                                            \
        const float f0 = u[s >> 1][t] * wa, f1 = u[s >> 1][t] * wb;            \
        int pp;                                                                \
        asm("v_cvt_pk_bf16_f32 %0, %1, %2" : "=v"(pp) : "v"(f0), "v"(f1));     \
        pk[t] = pp;                                                            \
      }                                                                        \
      const short8 e2s =                                                       \
          __builtin_bit_cast(short8, (vi4){pk[0], pk[1], pk[2], pk[3]});       \
      _Pragma("unroll")                                                        \
      for (int mt = 0; mt < 4; mt++)                                           \
        acc[mt] = __builtin_amdgcn_mfma_f32_16x16x32_bf16(                     \
            __builtin_bit_cast(short8, FC[mt * 8 + s]), e2s, acc[mt], 0, 0, 0);\
    }                                                                          \
    _Pragma("unroll")                                                          \
    for (int mt = 0; mt < 4; mt++) u[mt] = acc[mt];                            \
    if (npr < NP) {                                                            \
      const float qi = 0.25f * xiN, qj = 0.25f * xjN;                          \
      float c_, s_;                                                            \
      asm("v_cos_f32 %0, %1" : "=v"(c_) : "v"(qi));                            \
      asm("v_sin_f32 %0, %1" : "=v"(s_) : "v"(qi));                            \
      ci = c_; si = s_;                                                        \
      asm("v_cos_f32 %0, %1" : "=v"(c_) : "v"(qj));                            \
      asm("v_sin_f32 %0, %1" : "=v"(s_) : "v"(qj));                            \
      cj = c_; sj = s_;                                                        \
    }                                                                          \
    if ((pr_ & 3) == 3) { /* exact pow2 rescale (every 8 sites) */             \
      float nss = 0.f;                                                         \
      _Pragma("unroll")                                                        \
      for (int mt = 0; mt < 4; mt++)                                           \
        _Pragma("unroll")                                                      \
        for (int r = 0; r < 4; r++) nss += u[mt][r] * u[mt][r];                \
      nss += __shfl_xor(nss, 16);                                              \
      nss += __shfl_xor(nss, 32);                                              \
      const int eb = (__float_as_int(nss) >> 23) & 0xFF;                       \
      const float alpha = __int_as_float((127 - ((eb - 127) >> 1)) << 23);     \
      _Pragma("unroll")                                                        \
      for (int mt = 0; mt < 4; mt++)                                           \
        _Pragma("unroll")                                                      \
        for (int r = 0; r < 4; r++) u[mt][r] *= alpha;                         \
    }                                                                          \
  }

// ---- sweep: 256 blocks x 2 waves (16-sample chains); 256 pair-steps ----
// groups of 2 pairs (64KB) double-buffered, 1 barrier per group.
// XCD swizzle: XCDs 0-3 -> dir 0, XCDs 4-7 -> dir 1.
__global__ __launch_bounds__(128, 1) void sweep(const float* __restrict__ x,
                                                const float* __restrict__ left0,
                                                const float* __restrict__ right_last,
                                                const unsigned short* __restrict__ Wp,
                                                float* __restrict__ envL,
                                                float* __restrict__ envR,
                                                unsigned short* __restrict__ Rb16) {
  __shared__ float ring[2][2][PAIR_F];   // 128 KB
  const int bid = blockIdx.x;            // 0..255
  const int xcd = bid & 7;
  const int dir = xcd >> 2;
  const int slot = (xcd & 3) * 32 + (bid >> 3);   // 0..127 within dir
  const int tid = threadIdx.x;
  const int wave = tid >> 6;
  const int lane = tid & 63;
  const int g_ = lane >> 4, c = lane & 15;
  const int b = (slot * 2 + wave) * 16 + c;
  const float* xrow = x + (size_t)b * LL;

  const float* Wf = (const float*)(Wp + (size_t)dir * NP * PAIR_U16);

  // init env (fp32, exact normalize)
  vf4 u[4];
  {
    const float x0 = xrow[dir ? (LL - 1) : 0];
    const float qrev = 0.25f * x0;
    float cs, sn;
    asm("v_cos_f32 %0, %1" : "=v"(cs) : "v"(qrev));
    asm("v_sin_f32 %0, %1" : "=v"(sn) : "v"(qrev));
#pragma unroll
    for (int mt = 0; mt < 4; mt++)
#pragma unroll
      for (int r = 0; r < 4; r++) {
        const int n = 16 * mt + 4 * g_ + r;
        const float w0 = dir ? right_last[n * 2] : left0[n];
        const float w1 = dir ? right_last[n * 2 + 1] : left0[64 + n];
        u[mt][r] = cs * w0 + sn * w1;
      }
    float ss = 0.f;
#pragma unroll
    for (int mt = 0; mt < 4; mt++)
#pragma unroll
      for (int r = 0; r < 4; r++) ss += u[mt][r] * u[mt][r];
    ss += __shfl_xor(ss, 16);
    ss += __shfl_xor(ss, 32);
    const float a0 = 1.f / (sqrtf(ss) + 1e-8f);
#pragma unroll
    for (int mt = 0; mt < 4; mt++)
#pragma unroll
      for (int r = 0; r < 4; r++) u[mt][r] *= a0;
  }

  STAGE_GROUP(0, 0)

  // trig for pair 0
  float ci, si, cj, sj;
  {
    const float xi = xrow[dir ? 1022 : 1];
    const float xj = xrow[dir ? 1021 : 2];
    const float qi = 0.25f * xi, qj = 0.25f * xj;
    asm("v_cos_f32 %0, %1" : "=v"(ci) : "v"(qi));
    asm("v_sin_f32 %0, %1" : "=v"(si) : "v"(qi));
    asm("v_cos_f32 %0, %1" : "=v"(cj) : "v"(qj));
    asm("v_sin_f32 %0, %1" : "=v"(sj) : "v"(qj));
  }
  __syncthreads();

  for (int g = 0; g < 128; g++) {
    const int buf = g & 1;
    if (g < 127) STAGE_GROUP(g + 1, buf ^ 1)
    PBODY(2 * g, buf, 0)
    PBODY(2 * g + 1, buf, 1)
    __syncthreads();
  }

  // final exact normalize + store (f32 env + bf16 copy for centerk2)
  float nss = 0.f;
#pragma unroll
  for (int mt = 0; mt < 4; mt++)
#pragma unroll
    for (int r = 0; r < 4; r++) nss += u[mt][r] * u[mt][r];
  nss += __shfl_xor(nss, 16);
  nss += __shfl_xor(nss, 32);
  const float alpha = 1.f / (sqrtf(nss) + 1e-8f);

  float* eo = (dir ? envR : envL) + (size_t)b * 64;
#pragma unroll
  for (int mt = 0; mt < 4; mt++) {
    vf4 v;
#pragma unroll
    for (int r = 0; r < 4; r++) v[r] = u[mt][r] * alpha;
    *(vf4*)&eo[16 * mt + 4 * g_] = v;
    if (dir) {
      int p01, p23;
      asm("v_cvt_pk_bf16_f32 %0, %1, %2" : "=v"(p01) : "v"(v[0]), "v"(v[1]));
      asm("v_cvt_pk_bf16_f32 %0, %1, %2" : "=v"(p23) : "v"(v[2]), "v"(v[3]));
      *(vi2*)&Rb16[(size_t)b * 64 + 16 * mt + 4 * g_] = (vi2){p01, p23};
    }
  }
}

// ---- center contraction via MFMA: out[b,o] = L[b,:]·(C_o·R[b,:]^T) ----
__global__ __launch_bounds__(256) void centerk2(const float* __restrict__ envL,
                                                const unsigned short* __restrict__ Rb16,
                                                const unsigned short* __restrict__ Cf,
                                                float* __restrict__ Pp) {
  const int b0 = blockIdx.x * 16;
  const int tid = threadIdx.x;
  const int wave = tid >> 6;
  const int lane = tid & 63;
  const int g = lane >> 4, c = lane & 15;

  short8 rf[2];
#pragma unroll
  for (int s = 0; s < 2; s++)
    rf[s] = __builtin_bit_cast(short8,
        *(const ushort8*)&Rb16[(size_t)(b0 + c) * 64 + 32 * s + 8 * g]);

  vf4 Lv[4];
#pragma unroll
  for (int mt = 0; mt < 4; mt++)
    Lv[mt] = *(const vf4*)&envL[(size_t)(b0 + c) * 64 + 16 * mt + 4 * g];

  for (int oi = 0; oi < 32; oi++) {
    const int o = wave * 32 + oi;
    const unsigned short* cb = Cf + (size_t)(o * 8) * 64 * 8;
    vf4 acc[4];
#pragma unroll
    for (int mt = 0; mt < 4; mt++) {
      const short8 a0 = __builtin_bit_cast(short8,
          *(const ushort8*)&cb[(size_t)((mt * 2 + 0) * 64 + lane) * 8]);
      const short8 a1 = __builtin_bit_cast(short8,
          *(const ushort8*)&cb[(size_t)((mt * 2 + 1) * 64 + lane) * 8]);
      vf4 z = {0.f, 0.f, 0.f, 0.f};
      z = __builtin_amdgcn_mfma_f32_16x16x32_bf16(a0, rf[0], z, 0, 0, 0);
      z = __builtin_amdgcn_mfma_f32_16x16x32_bf16(a1, rf[1], z, 0, 0, 0);
      acc[mt] = z;
    }
    float ps = 0.f;
#pragma unroll
    for (int mt = 0; mt < 4; mt++)
#pragma unroll
      for (int r = 0; r < 4; r++) ps += Lv[mt][r] * acc[mt][r];
    ps += __shfl_xor(ps, 16);
    ps += __shfl_xor(ps, 32);
    if (g == 0) Pp[(size_t)(b0 + c) * 128 + o] = ps;
  }
}

// ---- row-normalize Pp -> out ----
__global__ __launch_bounds__(256) void combinek2(const float* __restrict__ P,
                                                 float* __restrict__ out) {
  const int row = blockIdx.x * 8 + (threadIdx.x >> 5);
  const int o0 = (threadIdx.x & 31) * 4;
  vf4 v = *(const vf4*)&P[(size_t)row * 128 + o0];
  float ss = v[0] * v[0] + v[1] * v[1] + v[2] * v[2] + v[3] * v[3];
#pragma unroll
  for (int m = 1; m < 32; m <<= 1) ss += __shfl_xor(ss, m);
  const float inv = 1.f / fmaxf(sqrtf(ss), 1e-12f);
  v *= inv;
  *(vf4*)&out[(size_t)row * 128 + o0] = v;
}

extern "C" void kernel_launch(void* const* d_in, const int* in_sizes, int n_in,
                              void* d_out, int out_size, void* d_ws, size_t ws_size,
                              hipStream_t stream) {
  const float* x = (const float*)d_in[0];
  const float* left0 = (const float*)d_in[1];
  const float* left_rest = (const float*)d_in[2];
  const float* center = (const float*)d_in[3];
  const float* right_rest = (const float*)d_in[4];
  const float* right_last = (const float*)d_in[5];
  float* out = (float*)d_out;

  char* wsb = (char*)d_ws;
  unsigned short* Wp = (unsigned short*)wsb;                  // 2*256*32KB = 16.8 MB
  float* envL = (float*)(Wp + (size_t)2 * NP * PAIR_U16);     // 1 MB
  float* envR = envL + (size_t)BBATCH * 64;                   // 1 MB
  unsigned short* Rb16 = (unsigned short*)(envR + (size_t)BBATCH * 64);  // 0.5 MB
  unsigned short* Cf = Rb16 + (size_t)BBATCH * 64;            // 1 MB
  float* Pp = (float*)(Cf + (size_t)OO * 8 * 64 * 8);         // 2 MB

  hipLaunchKernelGGL(prep_pair, dim3(NP, 2), dim3(256), 0, stream,
                     left_rest, right_rest, Wp);
  hipLaunchKernelGGL(prep2, dim3(OO), dim3(256), 0, stream, center, Cf);
  hipLaunchKernelGGL(sweep, dim3(256), dim3(128), 0, stream,
                     x, left0, right_last, Wp, envL, envR, Rb16);
  hipLaunchKernelGGL(centerk2, dim3(BBATCH / 16), dim3(256), 0, stream,
                     envL, Rb16, Cf, Pp);
  hipLaunchKernelGGL(combinek2, dim3(BBATCH / 8), dim3(256), 0, stream, Pp, out);
}